// Round 8
// baseline (148.943 us; speedup 1.0000x reference)
//
#include <hip/hip_runtime.h>

#define NSEG 17

// ---------------- ws layout ----------------
// [0,    272)            : int   counts[4][17]
// [512,  784)            : float coef[4][17]
// [1024,   1024+131072)  : uint8 seg0b[8*128*128]
// [132096, +32768)       : uint8 seg1b[8*64*64]
// [164864, +8192)        : uint8 seg2b[8*32*32]
// [173056, +2048)        : uint8 seg3b[8*16*16]

__global__ void init_accum(int* __restrict__ counts) {
    int t = threadIdx.x;
    if (t < 4 * NSEG) counts[t] = 0;
}

// One thread per scale-0 pixel: per-scale seg byte maps + per-scale counts.
__global__ __launch_bounds__(256) void seg_count_kernel(
    const int* __restrict__ labels,         // [8,512,512]
    const float* __restrict__ outputs_old,  // [8,OC,512,512]
    unsigned char* __restrict__ seg0b,
    unsigned char* __restrict__ seg1b,
    unsigned char* __restrict__ seg2b,
    unsigned char* __restrict__ seg3b,
    int* __restrict__ counts,               // [4][17]
    int OC)
{
    __shared__ int cbins[4 * NSEG];
    int t = threadIdx.x;
    if (t < 4 * NSEG) cbins[t] = 0;
    __syncthreads();

    int p = blockIdx.x * 256 + t;           // [0, 131072)
    int b = p >> 14;
    int y = (p >> 7) & 127;
    int x = p & 127;
    int y0 = y << 2, x0 = x << 2;           // sampled position in 512 grid

    int lbl = labels[(b << 18) + (y0 << 9) + x0];

    // thresholded argmax, first-index-of-max (jnp.argmax semantics)
    const float* base = outputs_old + (((size_t)b * OC) << 18) + (y0 << 9) + x0;
    float best; int bidx = 0;
    if (OC == 16) {                          // fast path: 16 independent loads in flight
        float v[16];
        #pragma unroll
        for (int c = 0; c < 16; ++c) v[c] = base[(size_t)c << 18];
        #pragma unroll
        for (int c = 0; c < 16; ++c) v[c] = (v[c] < 0.5f) ? 0.0f : v[c];
        best = v[0];
        #pragma unroll
        for (int c = 1; c < 16; ++c) if (v[c] > best) { best = v[c]; bidx = c; }
    } else {
        float v0 = base[0];
        best = (v0 < 0.5f) ? 0.0f : v0;
        #pragma unroll 4
        for (int c = 1; c < OC; ++c) {
            float v = base[(size_t)c << 18];
            v = (v < 0.5f) ? 0.0f : v;
            if (v > best) { best = v; bidx = c; }
        }
    }

    int nold = OC - 1;
    int pl = (lbl == 0) ? bidx : lbl;
    int seg = (pl <= nold) ? pl : (nold + 1);

    seg0b[p] = (unsigned char)seg;
    atomicAdd(&cbins[seg], 1);
    if (((y | x) & 1) == 0) {
        seg1b[(b << 12) + ((y >> 1) << 6) + (x >> 1)] = (unsigned char)seg;
        atomicAdd(&cbins[NSEG + seg], 1);
    }
    if (((y | x) & 3) == 0) {
        seg2b[(b << 10) + ((y >> 2) << 5) + (x >> 2)] = (unsigned char)seg;
        atomicAdd(&cbins[2 * NSEG + seg], 1);
    }
    if (((y | x) & 7) == 0) {
        seg3b[(b << 8) + ((y >> 3) << 4) + (x >> 3)] = (unsigned char)seg;
        atomicAdd(&cbins[3 * NSEG + seg], 1);
    }
    __syncthreads();
    if (t < 4 * NSEG) {
        int c = cbins[t];
        if (c) atomicAdd(&counts[t], c);
    }
}

// coef[s][g] = 0.25 * (s+1) * cls_w[g] / (counts[s][g] * C_s); also zeroes out[0].
__global__ void coef_kernel(const int* __restrict__ counts,
                            const int* __restrict__ p_ncls,
                            const int* __restrict__ p_nold,
                            int OC,
                            float* __restrict__ coef,
                            float* __restrict__ out)
{
    int t = threadIdx.x;
    if (t == 0) out[0] = 0.0f;
    if (t >= 4 * NSEG) return;
    int s = t / NSEG, g = t % NSEG;
    int nold = p_nold[0];
    if (nold < 1 || nold > 100) nold = OC - 1;       // sanity fallback
    int ncls = p_ncls[0];
    if (ncls <= nold || ncls > 1000) ncls = 21;      // sanity fallback
    float w = (g == 0) ? (float)nold / (float)ncls : ((g <= nold) ? 1.0f : 0.0f);
    int cnt = counts[t];
    float c = 0.0f;
    if (cnt > 0 && w > 0.0f)
        c = 0.25f * (float)(s + 1) * w / ((float)cnt * (float)(256 << s));
    coef[t] = c;
}

// One pixel-quad's weighted SSE contribution.
#define QUADACC(A, B, g, acc) do {                                  \
    float d_;                                                       \
    d_ = (A).x - (B).x; acc = fmaf(cf[(g) & 255u] * d_, d_, acc);   \
    d_ = (A).y - (B).y; acc = fmaf(cf[((g) >> 8) & 255u] * d_, d_, acc);  \
    d_ = (A).z - (B).z; acc = fmaf(cf[((g) >> 16) & 255u] * d_, d_, acc); \
    d_ = (A).w - (B).w; acc = fmaf(cf[(g) >> 24] * d_, d_, acc);    \
} while (0)

// Linear-streaming weighted SSE, deep-MLP version: all 24 loads (8 F float4,
// 8 O float4, 8 seg dwords) are issued as named values BEFORE any consume,
// so ~18KB/wave stays in flight. Block owns 2048 contiguous quads.
template <int S>
__device__ __forceinline__ float sq_stream(const float* __restrict__ F,
                                           const float* __restrict__ O,
                                           const unsigned* __restrict__ segq,
                                           const float* __restrict__ cf,  // LDS[17]
                                           int blk)
{
    constexpr int lqpi = 12 - 2 * S;        // log2 float4-quads per (b,c) plane
    constexpr int lgBC = lqpi + 8 + S;      // log2 quads per image (C * hw4)
    constexpr int hw4m = (1 << lqpi) - 1;

    const float4* pF = reinterpret_cast<const float4*>(F);
    const float4* pO = reinterpret_cast<const float4*>(O);
    int qb = blk * 2048 + (int)threadIdx.x;

#define SIDX(q) (((unsigned)((q) >> lgBC) << lqpi) | ((unsigned)(q) & (unsigned)hw4m))
    int q0 = qb +    0, q1 = qb +  256, q2 = qb +  512, q3 = qb +  768;
    int q4 = qb + 1024, q5 = qb + 1280, q6 = qb + 1536, q7 = qb + 1792;

    unsigned g0 = segq[SIDX(q0)], g1 = segq[SIDX(q1)];
    unsigned g2 = segq[SIDX(q2)], g3 = segq[SIDX(q3)];
    unsigned g4 = segq[SIDX(q4)], g5 = segq[SIDX(q5)];
    unsigned g6 = segq[SIDX(q6)], g7 = segq[SIDX(q7)];
    float4 A0 = pF[q0], A1 = pF[q1], A2 = pF[q2], A3 = pF[q3];
    float4 A4 = pF[q4], A5 = pF[q5], A6 = pF[q6], A7 = pF[q7];
    float4 B0 = pO[q0], B1 = pO[q1], B2 = pO[q2], B3 = pO[q3];
    float4 B4 = pO[q4], B5 = pO[q5], B6 = pO[q6], B7 = pO[q7];
#undef SIDX

    float acc0 = 0.0f, acc1 = 0.0f;
    QUADACC(A0, B0, g0, acc0);
    QUADACC(A1, B1, g1, acc1);
    QUADACC(A2, B2, g2, acc0);
    QUADACC(A3, B3, g3, acc1);
    QUADACC(A4, B4, g4, acc0);
    QUADACC(A5, B5, g5, acc1);
    QUADACC(A6, B6, g6, acc0);
    QUADACC(A7, B7, g7, acc1);
    return acc0 + acc1;
}

// Blocks: [0,4096) s0, [4096,6144) s1, [6144,7168) s2, [7168,7680) s3.
__global__ __launch_bounds__(256, 4) void sq_sum_kernel(
    const float* __restrict__ f0, const float* __restrict__ o0,
    const float* __restrict__ f1, const float* __restrict__ o1,
    const float* __restrict__ f2, const float* __restrict__ o2,
    const float* __restrict__ f3, const float* __restrict__ o3,
    const unsigned* __restrict__ seg0q, const unsigned* __restrict__ seg1q,
    const unsigned* __restrict__ seg2q, const unsigned* __restrict__ seg3q,
    const float* __restrict__ coef,   // [4][17]
    float* __restrict__ out)
{
    __shared__ float cf[NSEG];
    __shared__ float wsum[4];

    int blk = blockIdx.x;
    int s_idx = (blk < 4096) ? 0 : (blk < 6144) ? 1 : (blk < 7168) ? 2 : 3;
    if (threadIdx.x < NSEG) cf[threadIdx.x] = coef[s_idx * NSEG + threadIdx.x];
    __syncthreads();

    float acc;
    if (s_idx == 0)      acc = sq_stream<0>(f0, o0, seg0q, cf, blk);
    else if (s_idx == 1) acc = sq_stream<1>(f1, o1, seg1q, cf, blk - 4096);
    else if (s_idx == 2) acc = sq_stream<2>(f2, o2, seg2q, cf, blk - 6144);
    else                 acc = sq_stream<3>(f3, o3, seg3q, cf, blk - 7168);

    #pragma unroll
    for (int off = 32; off > 0; off >>= 1) acc += __shfl_down(acc, off, 64);
    if ((threadIdx.x & 63) == 0) wsum[threadIdx.x >> 6] = acc;
    __syncthreads();
    if (threadIdx.x == 0)
        atomicAdd(out, (wsum[0] + wsum[1]) + (wsum[2] + wsum[3]));
}

extern "C" void kernel_launch(void* const* d_in, const int* in_sizes, int n_in,
                              void* d_out, int out_size, void* d_ws, size_t ws_size,
                              hipStream_t stream) {
    // setup_inputs dict order:
    // labels, outputs_old, feat0, feat_old0, feat1, feat_old1,
    // feat2, feat_old2, feat3, feat_old3, num_class, num_old_class
    const int*   labels      = (const int*)d_in[0];
    const float* outputs_old = (const float*)d_in[1];
    const float* f0 = (const float*)d_in[2];
    const float* o0 = (const float*)d_in[3];
    const float* f1 = (const float*)d_in[4];
    const float* o1 = (const float*)d_in[5];
    const float* f2 = (const float*)d_in[6];
    const float* o2 = (const float*)d_in[7];
    const float* f3 = (const float*)d_in[8];
    const float* o3 = (const float*)d_in[9];
    const int* p_ncls = (const int*)d_in[10];
    const int* p_nold = (const int*)d_in[11];

    int OC = in_sizes[1] / in_sizes[0];   // outputs_old channels = num_old_class + 1

    char* ws = (char*)d_ws;
    int*   counts = (int*)ws;                       // 272 B
    float* coef   = (float*)(ws + 512);             // 272 B
    unsigned char* seg0b = (unsigned char*)(ws + 1024);
    unsigned char* seg1b = (unsigned char*)(ws + 132096);
    unsigned char* seg2b = (unsigned char*)(ws + 164864);
    unsigned char* seg3b = (unsigned char*)(ws + 173056);

    hipLaunchKernelGGL(init_accum, dim3(1), dim3(128), 0, stream, counts);
    hipLaunchKernelGGL(seg_count_kernel, dim3(512), dim3(256), 0, stream,
                       labels, outputs_old, seg0b, seg1b, seg2b, seg3b, counts, OC);
    hipLaunchKernelGGL(coef_kernel, dim3(1), dim3(128), 0, stream,
                       counts, p_ncls, p_nold, OC, coef, (float*)d_out);
    hipLaunchKernelGGL(sq_sum_kernel, dim3(7680), dim3(256), 0, stream,
                       f0, o0, f1, o1, f2, o2, f3, o3,
                       (const unsigned*)seg0b, (const unsigned*)seg1b,
                       (const unsigned*)seg2b, (const unsigned*)seg3b,
                       coef, (float*)d_out);
}

// Round 9
// 117.556 us; speedup vs baseline: 1.2670x; 1.2670x over previous
//
#include <hip/hip_runtime.h>

#define NSEG 17

// ---------------- ws layout ----------------
// [0,    272)            : int   counts[4][17]
// [1024,   1024+131072)  : uint8 seg0b[8*128*128]
// [132096, +32768)       : uint8 seg1b[8*64*64]
// [164864, +8192)        : uint8 seg2b[8*32*32]
// [173056, +2048)        : uint8 seg3b[8*16*16]

__global__ void init_accum(int* __restrict__ counts, float* __restrict__ out) {
    int t = threadIdx.x;
    if (t < 4 * NSEG) counts[t] = 0;
    if (t == 0) out[0] = 0.0f;
}

// One thread per scale-0 pixel: per-scale seg byte maps + per-scale counts.
__global__ __launch_bounds__(256) void seg_count_kernel(
    const int* __restrict__ labels,         // [8,512,512]
    const float* __restrict__ outputs_old,  // [8,OC,512,512]
    unsigned char* __restrict__ seg0b,
    unsigned char* __restrict__ seg1b,
    unsigned char* __restrict__ seg2b,
    unsigned char* __restrict__ seg3b,
    int* __restrict__ counts,               // [4][17]
    int OC)
{
    __shared__ int cbins[4 * NSEG];
    int t = threadIdx.x;
    if (t < 4 * NSEG) cbins[t] = 0;
    __syncthreads();

    int p = blockIdx.x * 256 + t;           // [0, 131072)
    int b = p >> 14;
    int y = (p >> 7) & 127;
    int x = p & 127;
    int y0 = y << 2, x0 = x << 2;           // sampled position in 512 grid

    int lbl = labels[(b << 18) + (y0 << 9) + x0];

    // thresholded argmax, first-index-of-max (jnp.argmax semantics)
    const float* base = outputs_old + (((size_t)b * OC) << 18) + (y0 << 9) + x0;
    float best; int bidx = 0;
    if (OC == 16) {                          // fast path: 16 independent loads in flight
        float v[16];
        #pragma unroll
        for (int c = 0; c < 16; ++c) v[c] = base[(size_t)c << 18];
        #pragma unroll
        for (int c = 0; c < 16; ++c) v[c] = (v[c] < 0.5f) ? 0.0f : v[c];
        best = v[0];
        #pragma unroll
        for (int c = 1; c < 16; ++c) if (v[c] > best) { best = v[c]; bidx = c; }
    } else {
        float v0 = base[0];
        best = (v0 < 0.5f) ? 0.0f : v0;
        #pragma unroll 4
        for (int c = 1; c < OC; ++c) {
            float v = base[(size_t)c << 18];
            v = (v < 0.5f) ? 0.0f : v;
            if (v > best) { best = v; bidx = c; }
        }
    }

    int nold = OC - 1;
    int pl = (lbl == 0) ? bidx : lbl;
    int seg = (pl <= nold) ? pl : (nold + 1);

    seg0b[p] = (unsigned char)seg;
    atomicAdd(&cbins[seg], 1);
    if (((y | x) & 1) == 0) {
        seg1b[(b << 12) + ((y >> 1) << 6) + (x >> 1)] = (unsigned char)seg;
        atomicAdd(&cbins[NSEG + seg], 1);
    }
    if (((y | x) & 3) == 0) {
        seg2b[(b << 10) + ((y >> 2) << 5) + (x >> 2)] = (unsigned char)seg;
        atomicAdd(&cbins[2 * NSEG + seg], 1);
    }
    if (((y | x) & 7) == 0) {
        seg3b[(b << 8) + ((y >> 3) << 4) + (x >> 3)] = (unsigned char)seg;
        atomicAdd(&cbins[3 * NSEG + seg], 1);
    }
    __syncthreads();
    if (t < 4 * NSEG) {
        int c = cbins[t];
        if (c) atomicAdd(&counts[t], c);
    }
}

// Linear-streaming weighted SSE (R7's best-measured body, unchanged).
// Each block owns 4096 contiguous float4-quads (64 KB of F + 64 KB of O,
// sequential HBM pattern). Per-pixel coefficient from a 17-entry LDS table
// (consecutive words -> 17 distinct banks, broadcast on duplicates).
template <int S>
__device__ __forceinline__ float sq_stream(const float* __restrict__ F,
                                           const float* __restrict__ O,
                                           const unsigned* __restrict__ segq,
                                           const float* __restrict__ cf,  // LDS[17]
                                           int blk)
{
    constexpr int lqpi = 12 - 2 * S;        // log2 float4-quads per (b,c) plane
    constexpr int lgBC = lqpi + 8 + S;      // log2 quads per image (C * hw4)
    constexpr int hw4m = (1 << lqpi) - 1;

    const float4* pF = reinterpret_cast<const float4*>(F);
    const float4* pO = reinterpret_cast<const float4*>(O);
    int qbase = blk * 4096 + (int)threadIdx.x;

    float acc = 0.0f;
    #pragma unroll 2
    for (int k = 0; k < 16; k += 4) {
        int q0 = qbase + (k + 0) * 256;
        int q1 = qbase + (k + 1) * 256;
        int q2 = qbase + (k + 2) * 256;
        int q3 = qbase + (k + 3) * 256;
        unsigned g0 = segq[((q0 >> lgBC) << lqpi) | (q0 & hw4m)];
        unsigned g1 = segq[((q1 >> lgBC) << lqpi) | (q1 & hw4m)];
        unsigned g2 = segq[((q2 >> lgBC) << lqpi) | (q2 & hw4m)];
        unsigned g3 = segq[((q3 >> lgBC) << lqpi) | (q3 & hw4m)];
        float4 A0 = pF[q0], A1 = pF[q1], A2 = pF[q2], A3 = pF[q3];
        float4 B0 = pO[q0], B1 = pO[q1], B2 = pO[q2], B3 = pO[q3];
        float d, v;
        d = A0.x - B0.x; v  = cf[g0 & 255u]         * (d * d);
        d = A0.y - B0.y; v += cf[(g0 >> 8) & 255u]  * (d * d);
        d = A0.z - B0.z; v += cf[(g0 >> 16) & 255u] * (d * d);
        d = A0.w - B0.w; v += cf[g0 >> 24]          * (d * d);
        acc += v;
        d = A1.x - B1.x; v  = cf[g1 & 255u]         * (d * d);
        d = A1.y - B1.y; v += cf[(g1 >> 8) & 255u]  * (d * d);
        d = A1.z - B1.z; v += cf[(g1 >> 16) & 255u] * (d * d);
        d = A1.w - B1.w; v += cf[g1 >> 24]          * (d * d);
        acc += v;
        d = A2.x - B2.x; v  = cf[g2 & 255u]         * (d * d);
        d = A2.y - B2.y; v += cf[(g2 >> 8) & 255u]  * (d * d);
        d = A2.z - B2.z; v += cf[(g2 >> 16) & 255u] * (d * d);
        d = A2.w - B2.w; v += cf[g2 >> 24]          * (d * d);
        acc += v;
        d = A3.x - B3.x; v  = cf[g3 & 255u]         * (d * d);
        d = A3.y - B3.y; v += cf[(g3 >> 8) & 255u]  * (d * d);
        d = A3.z - B3.z; v += cf[(g3 >> 16) & 255u] * (d * d);
        d = A3.w - B3.w; v += cf[g3 >> 24]          * (d * d);
        acc += v;
    }
    return acc;
}

// Blocks: [0,2048) s0, [2048,3072) s1, [3072,3584) s2, [3584,3840) s3.
// Prologue computes cf[17] in-block from counts (replaces the coef kernel).
__global__ __launch_bounds__(256) void sq_sum_kernel(
    const float* __restrict__ f0, const float* __restrict__ o0,
    const float* __restrict__ f1, const float* __restrict__ o1,
    const float* __restrict__ f2, const float* __restrict__ o2,
    const float* __restrict__ f3, const float* __restrict__ o3,
    const unsigned* __restrict__ seg0q, const unsigned* __restrict__ seg1q,
    const unsigned* __restrict__ seg2q, const unsigned* __restrict__ seg3q,
    const int* __restrict__ counts,   // [4][17]
    const int* __restrict__ p_ncls,
    const int* __restrict__ p_nold,
    int OC,
    float* __restrict__ out)
{
    __shared__ float cf[NSEG];
    __shared__ float wsum[4];

    int blk = blockIdx.x;
    int s_idx = (blk < 2048) ? 0 : (blk < 3072) ? 1 : (blk < 3584) ? 2 : 3;

    if (threadIdx.x < NSEG) {
        int g = threadIdx.x;
        int nold = p_nold[0];
        if (nold < 1 || nold > 100) nold = OC - 1;   // sanity fallback
        int ncls = p_ncls[0];
        if (ncls <= nold || ncls > 1000) ncls = 21;  // sanity fallback
        float w = (g == 0) ? (float)nold / (float)ncls
                           : ((g <= nold) ? 1.0f : 0.0f);
        int cnt = counts[s_idx * NSEG + g];
        float c = 0.0f;
        if (cnt > 0 && w > 0.0f)
            c = 0.25f * (float)(s_idx + 1) * w /
                ((float)cnt * (float)(256 << s_idx));
        cf[g] = c;
    }
    __syncthreads();

    float acc;
    if (s_idx == 0)      acc = sq_stream<0>(f0, o0, seg0q, cf, blk);
    else if (s_idx == 1) acc = sq_stream<1>(f1, o1, seg1q, cf, blk - 2048);
    else if (s_idx == 2) acc = sq_stream<2>(f2, o2, seg2q, cf, blk - 3072);
    else                 acc = sq_stream<3>(f3, o3, seg3q, cf, blk - 3584);

    #pragma unroll
    for (int off = 32; off > 0; off >>= 1) acc += __shfl_down(acc, off, 64);
    if ((threadIdx.x & 63) == 0) wsum[threadIdx.x >> 6] = acc;
    __syncthreads();
    if (threadIdx.x == 0)
        atomicAdd(out, (wsum[0] + wsum[1]) + (wsum[2] + wsum[3]));
}

extern "C" void kernel_launch(void* const* d_in, const int* in_sizes, int n_in,
                              void* d_out, int out_size, void* d_ws, size_t ws_size,
                              hipStream_t stream) {
    // setup_inputs dict order:
    // labels, outputs_old, feat0, feat_old0, feat1, feat_old1,
    // feat2, feat_old2, feat3, feat_old3, num_class, num_old_class
    const int*   labels      = (const int*)d_in[0];
    const float* outputs_old = (const float*)d_in[1];
    const float* f0 = (const float*)d_in[2];
    const float* o0 = (const float*)d_in[3];
    const float* f1 = (const float*)d_in[4];
    const float* o1 = (const float*)d_in[5];
    const float* f2 = (const float*)d_in[6];
    const float* o2 = (const float*)d_in[7];
    const float* f3 = (const float*)d_in[8];
    const float* o3 = (const float*)d_in[9];
    const int* p_ncls = (const int*)d_in[10];
    const int* p_nold = (const int*)d_in[11];

    int OC = in_sizes[1] / in_sizes[0];   // outputs_old channels = num_old_class + 1

    char* ws = (char*)d_ws;
    int*   counts = (int*)ws;                       // 272 B
    unsigned char* seg0b = (unsigned char*)(ws + 1024);
    unsigned char* seg1b = (unsigned char*)(ws + 132096);
    unsigned char* seg2b = (unsigned char*)(ws + 164864);
    unsigned char* seg3b = (unsigned char*)(ws + 173056);

    hipLaunchKernelGGL(init_accum, dim3(1), dim3(128), 0, stream,
                       counts, (float*)d_out);
    hipLaunchKernelGGL(seg_count_kernel, dim3(512), dim3(256), 0, stream,
                       labels, outputs_old, seg0b, seg1b, seg2b, seg3b, counts, OC);
    hipLaunchKernelGGL(sq_sum_kernel, dim3(3840), dim3(256), 0, stream,
                       f0, o0, f1, o1, f2, o2, f3, o3,
                       (const unsigned*)seg0b, (const unsigned*)seg1b,
                       (const unsigned*)seg2b, (const unsigned*)seg3b,
                       counts, p_ncls, p_nold, OC, (float*)d_out);
}

// Round 10
// 117.347 us; speedup vs baseline: 1.2693x; 1.0018x over previous
//
#include <hip/hip_runtime.h>

#define NSEG 17

// ---------------- ws layout ----------------
// [0,    272)            : int   counts[4][17]
// [1024,   1024+131072)  : uint8 seg0b[8*128*128]
// [132096, +32768)       : uint8 seg1b[8*64*64]
// [164864, +8192)        : uint8 seg2b[8*32*32]
// [173056, +2048)        : uint8 seg3b[8*16*16]

__global__ void init_accum(int* __restrict__ counts, float* __restrict__ out) {
    int t = threadIdx.x;
    if (t < 4 * NSEG) counts[t] = 0;
    if (t == 0) out[0] = 0.0f;
}

// ---- OC==16 fast path: 4 lanes per pixel, shuffle-merged argmax. ----
// 512 blocks x 1024 threads -> 2 blocks/CU, 32 waves/CU (vs 8 before).
__global__ __launch_bounds__(1024) void seg_count16_kernel(
    const int* __restrict__ labels,         // [8,512,512]
    const float* __restrict__ outputs_old,  // [8,16,512,512]
    unsigned char* __restrict__ seg0b,
    unsigned char* __restrict__ seg1b,
    unsigned char* __restrict__ seg2b,
    unsigned char* __restrict__ seg3b,
    int* __restrict__ counts)               // [4][17]
{
    __shared__ int cbins[4 * NSEG];
    int t = threadIdx.x;
    if (t < 4 * NSEG) cbins[t] = 0;
    __syncthreads();

    int cg  = t & 3;                        // channel group (4 channels each)
    int pli = t >> 2;                       // pixel-local index 0..255
    int p   = blockIdx.x * 256 + pli;       // [0, 131072)
    int b = p >> 14;
    int y = (p >> 7) & 127;
    int x = p & 127;
    int y0 = y << 2, x0 = x << 2;           // sampled position in 512 grid

    const float* base = outputs_old + (((size_t)b * 16) << 18) + (y0 << 9) + x0;
    int c0 = cg << 2;
    float v0 = base[(size_t)(c0 + 0) << 18];
    float v1 = base[(size_t)(c0 + 1) << 18];
    float v2 = base[(size_t)(c0 + 2) << 18];
    float v3 = base[(size_t)(c0 + 3) << 18];
    v0 = (v0 < 0.5f) ? 0.0f : v0;
    v1 = (v1 < 0.5f) ? 0.0f : v1;
    v2 = (v2 < 0.5f) ? 0.0f : v2;
    v3 = (v3 < 0.5f) ? 0.0f : v3;

    // in-lane first-index argmax over this lane's 4 channels
    float best = v0; int bi = c0;
    if (v1 > best) { best = v1; bi = c0 + 1; }
    if (v2 > best) { best = v2; bi = c0 + 2; }
    if (v3 > best) { best = v3; bi = c0 + 3; }

    // merge across the 4 cg lanes (lane bits 0-1); min-index on ties
    #pragma unroll
    for (int m = 1; m <= 2; m <<= 1) {
        float ov = __shfl_xor(best, m, 64);
        int   oi = __shfl_xor(bi,   m, 64);
        if (ov > best || (ov == best && oi < bi)) { best = ov; bi = oi; }
    }

    if (cg == 0) {
        int lbl = labels[(b << 18) + (y0 << 9) + x0];
        int pl = (lbl == 0) ? bi : lbl;
        int seg = (pl <= 15) ? pl : 16;

        seg0b[p] = (unsigned char)seg;
        atomicAdd(&cbins[seg], 1);
        if (((y | x) & 1) == 0) {
            seg1b[(b << 12) + ((y >> 1) << 6) + (x >> 1)] = (unsigned char)seg;
            atomicAdd(&cbins[NSEG + seg], 1);
        }
        if (((y | x) & 3) == 0) {
            seg2b[(b << 10) + ((y >> 2) << 5) + (x >> 2)] = (unsigned char)seg;
            atomicAdd(&cbins[2 * NSEG + seg], 1);
        }
        if (((y | x) & 7) == 0) {
            seg3b[(b << 8) + ((y >> 3) << 4) + (x >> 3)] = (unsigned char)seg;
            atomicAdd(&cbins[3 * NSEG + seg], 1);
        }
    }
    __syncthreads();
    if (t < 4 * NSEG) {
        int c = cbins[t];
        if (c) atomicAdd(&counts[t], c);
    }
}

// ---- generic fallback (any OC), one thread per pixel (R9 version) ----
__global__ __launch_bounds__(256) void seg_count_kernel(
    const int* __restrict__ labels,
    const float* __restrict__ outputs_old,
    unsigned char* __restrict__ seg0b,
    unsigned char* __restrict__ seg1b,
    unsigned char* __restrict__ seg2b,
    unsigned char* __restrict__ seg3b,
    int* __restrict__ counts,
    int OC)
{
    __shared__ int cbins[4 * NSEG];
    int t = threadIdx.x;
    if (t < 4 * NSEG) cbins[t] = 0;
    __syncthreads();

    int p = blockIdx.x * 256 + t;
    int b = p >> 14;
    int y = (p >> 7) & 127;
    int x = p & 127;
    int y0 = y << 2, x0 = x << 2;

    int lbl = labels[(b << 18) + (y0 << 9) + x0];

    const float* base = outputs_old + (((size_t)b * OC) << 18) + (y0 << 9) + x0;
    float v0 = base[0];
    float best = (v0 < 0.5f) ? 0.0f : v0;
    int bidx = 0;
    #pragma unroll 4
    for (int c = 1; c < OC; ++c) {
        float v = base[(size_t)c << 18];
        v = (v < 0.5f) ? 0.0f : v;
        if (v > best) { best = v; bidx = c; }
    }

    int nold = OC - 1;
    int pl = (lbl == 0) ? bidx : lbl;
    int seg = (pl <= nold) ? pl : (nold + 1);

    seg0b[p] = (unsigned char)seg;
    atomicAdd(&cbins[seg], 1);
    if (((y | x) & 1) == 0) {
        seg1b[(b << 12) + ((y >> 1) << 6) + (x >> 1)] = (unsigned char)seg;
        atomicAdd(&cbins[NSEG + seg], 1);
    }
    if (((y | x) & 3) == 0) {
        seg2b[(b << 10) + ((y >> 2) << 5) + (x >> 2)] = (unsigned char)seg;
        atomicAdd(&cbins[2 * NSEG + seg], 1);
    }
    if (((y | x) & 7) == 0) {
        seg3b[(b << 8) + ((y >> 3) << 4) + (x >> 3)] = (unsigned char)seg;
        atomicAdd(&cbins[3 * NSEG + seg], 1);
    }
    __syncthreads();
    if (t < 4 * NSEG) {
        int c = cbins[t];
        if (c) atomicAdd(&counts[t], c);
    }
}

// Linear-streaming weighted SSE (R7/R9 best-measured body, unchanged).
template <int S>
__device__ __forceinline__ float sq_stream(const float* __restrict__ F,
                                           const float* __restrict__ O,
                                           const unsigned* __restrict__ segq,
                                           const float* __restrict__ cf,  // LDS[17]
                                           int blk)
{
    constexpr int lqpi = 12 - 2 * S;        // log2 float4-quads per (b,c) plane
    constexpr int lgBC = lqpi + 8 + S;      // log2 quads per image (C * hw4)
    constexpr int hw4m = (1 << lqpi) - 1;

    const float4* pF = reinterpret_cast<const float4*>(F);
    const float4* pO = reinterpret_cast<const float4*>(O);
    int qbase = blk * 4096 + (int)threadIdx.x;

    float acc = 0.0f;
    #pragma unroll 2
    for (int k = 0; k < 16; k += 4) {
        int q0 = qbase + (k + 0) * 256;
        int q1 = qbase + (k + 1) * 256;
        int q2 = qbase + (k + 2) * 256;
        int q3 = qbase + (k + 3) * 256;
        unsigned g0 = segq[((q0 >> lgBC) << lqpi) | (q0 & hw4m)];
        unsigned g1 = segq[((q1 >> lgBC) << lqpi) | (q1 & hw4m)];
        unsigned g2 = segq[((q2 >> lgBC) << lqpi) | (q2 & hw4m)];
        unsigned g3 = segq[((q3 >> lgBC) << lqpi) | (q3 & hw4m)];
        float4 A0 = pF[q0], A1 = pF[q1], A2 = pF[q2], A3 = pF[q3];
        float4 B0 = pO[q0], B1 = pO[q1], B2 = pO[q2], B3 = pO[q3];
        float d, v;
        d = A0.x - B0.x; v  = cf[g0 & 255u]         * (d * d);
        d = A0.y - B0.y; v += cf[(g0 >> 8) & 255u]  * (d * d);
        d = A0.z - B0.z; v += cf[(g0 >> 16) & 255u] * (d * d);
        d = A0.w - B0.w; v += cf[g0 >> 24]          * (d * d);
        acc += v;
        d = A1.x - B1.x; v  = cf[g1 & 255u]         * (d * d);
        d = A1.y - B1.y; v += cf[(g1 >> 8) & 255u]  * (d * d);
        d = A1.z - B1.z; v += cf[(g1 >> 16) & 255u] * (d * d);
        d = A1.w - B1.w; v += cf[g1 >> 24]          * (d * d);
        acc += v;
        d = A2.x - B2.x; v  = cf[g2 & 255u]         * (d * d);
        d = A2.y - B2.y; v += cf[(g2 >> 8) & 255u]  * (d * d);
        d = A2.z - B2.z; v += cf[(g2 >> 16) & 255u] * (d * d);
        d = A2.w - B2.w; v += cf[g2 >> 24]          * (d * d);
        acc += v;
        d = A3.x - B3.x; v  = cf[g3 & 255u]         * (d * d);
        d = A3.y - B3.y; v += cf[(g3 >> 8) & 255u]  * (d * d);
        d = A3.z - B3.z; v += cf[(g3 >> 16) & 255u] * (d * d);
        d = A3.w - B3.w; v += cf[g3 >> 24]          * (d * d);
        acc += v;
    }
    return acc;
}

// Blocks: [0,2048) s0, [2048,3072) s1, [3072,3584) s2, [3584,3840) s3.
__global__ __launch_bounds__(256) void sq_sum_kernel(
    const float* __restrict__ f0, const float* __restrict__ o0,
    const float* __restrict__ f1, const float* __restrict__ o1,
    const float* __restrict__ f2, const float* __restrict__ o2,
    const float* __restrict__ f3, const float* __restrict__ o3,
    const unsigned* __restrict__ seg0q, const unsigned* __restrict__ seg1q,
    const unsigned* __restrict__ seg2q, const unsigned* __restrict__ seg3q,
    const int* __restrict__ counts,   // [4][17]
    const int* __restrict__ p_ncls,
    const int* __restrict__ p_nold,
    int OC,
    float* __restrict__ out)
{
    __shared__ float cf[NSEG];
    __shared__ float wsum[4];

    int blk = blockIdx.x;
    int s_idx = (blk < 2048) ? 0 : (blk < 3072) ? 1 : (blk < 3584) ? 2 : 3;

    if (threadIdx.x < NSEG) {
        int g = threadIdx.x;
        int nold = p_nold[0];
        if (nold < 1 || nold > 100) nold = OC - 1;   // sanity fallback
        int ncls = p_ncls[0];
        if (ncls <= nold || ncls > 1000) ncls = 21;  // sanity fallback
        float w = (g == 0) ? (float)nold / (float)ncls
                           : ((g <= nold) ? 1.0f : 0.0f);
        int cnt = counts[s_idx * NSEG + g];
        float c = 0.0f;
        if (cnt > 0 && w > 0.0f)
            c = 0.25f * (float)(s_idx + 1) * w /
                ((float)cnt * (float)(256 << s_idx));
        cf[g] = c;
    }
    __syncthreads();

    float acc;
    if (s_idx == 0)      acc = sq_stream<0>(f0, o0, seg0q, cf, blk);
    else if (s_idx == 1) acc = sq_stream<1>(f1, o1, seg1q, cf, blk - 2048);
    else if (s_idx == 2) acc = sq_stream<2>(f2, o2, seg2q, cf, blk - 3072);
    else                 acc = sq_stream<3>(f3, o3, seg3q, cf, blk - 3584);

    #pragma unroll
    for (int off = 32; off > 0; off >>= 1) acc += __shfl_down(acc, off, 64);
    if ((threadIdx.x & 63) == 0) wsum[threadIdx.x >> 6] = acc;
    __syncthreads();
    if (threadIdx.x == 0)
        atomicAdd(out, (wsum[0] + wsum[1]) + (wsum[2] + wsum[3]));
}

extern "C" void kernel_launch(void* const* d_in, const int* in_sizes, int n_in,
                              void* d_out, int out_size, void* d_ws, size_t ws_size,
                              hipStream_t stream) {
    // setup_inputs dict order:
    // labels, outputs_old, feat0, feat_old0, feat1, feat_old1,
    // feat2, feat_old2, feat3, feat_old3, num_class, num_old_class
    const int*   labels      = (const int*)d_in[0];
    const float* outputs_old = (const float*)d_in[1];
    const float* f0 = (const float*)d_in[2];
    const float* o0 = (const float*)d_in[3];
    const float* f1 = (const float*)d_in[4];
    const float* o1 = (const float*)d_in[5];
    const float* f2 = (const float*)d_in[6];
    const float* o2 = (const float*)d_in[7];
    const float* f3 = (const float*)d_in[8];
    const float* o3 = (const float*)d_in[9];
    const int* p_ncls = (const int*)d_in[10];
    const int* p_nold = (const int*)d_in[11];

    int OC = in_sizes[1] / in_sizes[0];   // outputs_old channels = num_old_class + 1

    char* ws = (char*)d_ws;
    int*   counts = (int*)ws;                       // 272 B
    unsigned char* seg0b = (unsigned char*)(ws + 1024);
    unsigned char* seg1b = (unsigned char*)(ws + 132096);
    unsigned char* seg2b = (unsigned char*)(ws + 164864);
    unsigned char* seg3b = (unsigned char*)(ws + 173056);

    hipLaunchKernelGGL(init_accum, dim3(1), dim3(128), 0, stream,
                       counts, (float*)d_out);
    if (OC == 16) {
        hipLaunchKernelGGL(seg_count16_kernel, dim3(512), dim3(1024), 0, stream,
                           labels, outputs_old, seg0b, seg1b, seg2b, seg3b, counts);
    } else {
        hipLaunchKernelGGL(seg_count_kernel, dim3(512), dim3(256), 0, stream,
                           labels, outputs_old, seg0b, seg1b, seg2b, seg3b, counts, OC);
    }
    hipLaunchKernelGGL(sq_sum_kernel, dim3(3840), dim3(256), 0, stream,
                       f0, o0, f1, o1, f2, o2, f3, o3,
                       (const unsigned*)seg0b, (const unsigned*)seg1b,
                       (const unsigned*)seg2b, (const unsigned*)seg3b,
                       counts, p_ncls, p_nold, OC, (float*)d_out);
}

// Round 11
// 115.336 us; speedup vs baseline: 1.2914x; 1.0174x over previous
//
#include <hip/hip_runtime.h>

#define NSEG 17

// ---------------- ws layout ----------------
// [0,    272)            : int   counts[4][17]
// [1024,   1024+131072)  : uint8 seg0b[8*128*128]
// [132096, +32768)       : uint8 seg1b[8*64*64]
// [164864, +8192)        : uint8 seg2b[8*32*32]
// [173056, +2048)        : uint8 seg3b[8*16*16]

__global__ void init_accum(int* __restrict__ counts, float* __restrict__ out) {
    int t = threadIdx.x;
    if (t < 4 * NSEG) counts[t] = 0;
    if (t == 0) out[0] = 0.0f;
}

// ---- OC==16 fast path: 4 lanes per pixel, shuffle-merged argmax. ----
__global__ __launch_bounds__(1024) void seg_count16_kernel(
    const int* __restrict__ labels,         // [8,512,512]
    const float* __restrict__ outputs_old,  // [8,16,512,512]
    unsigned char* __restrict__ seg0b,
    unsigned char* __restrict__ seg1b,
    unsigned char* __restrict__ seg2b,
    unsigned char* __restrict__ seg3b,
    int* __restrict__ counts)               // [4][17]
{
    __shared__ int cbins[4 * NSEG];
    int t = threadIdx.x;
    if (t < 4 * NSEG) cbins[t] = 0;
    __syncthreads();

    int cg  = t & 3;                        // channel group (4 channels each)
    int pli = t >> 2;                       // pixel-local index 0..255
    int p   = blockIdx.x * 256 + pli;       // [0, 131072)
    int b = p >> 14;
    int y = (p >> 7) & 127;
    int x = p & 127;
    int y0 = y << 2, x0 = x << 2;           // sampled position in 512 grid

    const float* base = outputs_old + (((size_t)b * 16) << 18) + (y0 << 9) + x0;
    int c0 = cg << 2;
    float v0 = base[(size_t)(c0 + 0) << 18];
    float v1 = base[(size_t)(c0 + 1) << 18];
    float v2 = base[(size_t)(c0 + 2) << 18];
    float v3 = base[(size_t)(c0 + 3) << 18];
    v0 = (v0 < 0.5f) ? 0.0f : v0;
    v1 = (v1 < 0.5f) ? 0.0f : v1;
    v2 = (v2 < 0.5f) ? 0.0f : v2;
    v3 = (v3 < 0.5f) ? 0.0f : v3;

    // in-lane first-index argmax over this lane's 4 channels
    float best = v0; int bi = c0;
    if (v1 > best) { best = v1; bi = c0 + 1; }
    if (v2 > best) { best = v2; bi = c0 + 2; }
    if (v3 > best) { best = v3; bi = c0 + 3; }

    // merge across the 4 cg lanes (lane bits 0-1); min-index on ties
    #pragma unroll
    for (int m = 1; m <= 2; m <<= 1) {
        float ov = __shfl_xor(best, m, 64);
        int   oi = __shfl_xor(bi,   m, 64);
        if (ov > best || (ov == best && oi < bi)) { best = ov; bi = oi; }
    }

    if (cg == 0) {
        int lbl = labels[(b << 18) + (y0 << 9) + x0];
        int pl = (lbl == 0) ? bi : lbl;
        int seg = (pl <= 15) ? pl : 16;

        seg0b[p] = (unsigned char)seg;
        atomicAdd(&cbins[seg], 1);
        if (((y | x) & 1) == 0) {
            seg1b[(b << 12) + ((y >> 1) << 6) + (x >> 1)] = (unsigned char)seg;
            atomicAdd(&cbins[NSEG + seg], 1);
        }
        if (((y | x) & 3) == 0) {
            seg2b[(b << 10) + ((y >> 2) << 5) + (x >> 2)] = (unsigned char)seg;
            atomicAdd(&cbins[2 * NSEG + seg], 1);
        }
        if (((y | x) & 7) == 0) {
            seg3b[(b << 8) + ((y >> 3) << 4) + (x >> 3)] = (unsigned char)seg;
            atomicAdd(&cbins[3 * NSEG + seg], 1);
        }
    }
    __syncthreads();
    if (t < 4 * NSEG) {
        int c = cbins[t];
        if (c) atomicAdd(&counts[t], c);
    }
}

// ---- generic fallback (any OC), one thread per pixel ----
__global__ __launch_bounds__(256) void seg_count_kernel(
    const int* __restrict__ labels,
    const float* __restrict__ outputs_old,
    unsigned char* __restrict__ seg0b,
    unsigned char* __restrict__ seg1b,
    unsigned char* __restrict__ seg2b,
    unsigned char* __restrict__ seg3b,
    int* __restrict__ counts,
    int OC)
{
    __shared__ int cbins[4 * NSEG];
    int t = threadIdx.x;
    if (t < 4 * NSEG) cbins[t] = 0;
    __syncthreads();

    int p = blockIdx.x * 256 + t;
    int b = p >> 14;
    int y = (p >> 7) & 127;
    int x = p & 127;
    int y0 = y << 2, x0 = x << 2;

    int lbl = labels[(b << 18) + (y0 << 9) + x0];

    const float* base = outputs_old + (((size_t)b * OC) << 18) + (y0 << 9) + x0;
    float v0 = base[0];
    float best = (v0 < 0.5f) ? 0.0f : v0;
    int bidx = 0;
    #pragma unroll 4
    for (int c = 1; c < OC; ++c) {
        float v = base[(size_t)c << 18];
        v = (v < 0.5f) ? 0.0f : v;
        if (v > best) { best = v; bidx = c; }
    }

    int nold = OC - 1;
    int pl = (lbl == 0) ? bidx : lbl;
    int seg = (pl <= nold) ? pl : (nold + 1);

    seg0b[p] = (unsigned char)seg;
    atomicAdd(&cbins[seg], 1);
    if (((y | x) & 1) == 0) {
        seg1b[(b << 12) + ((y >> 1) << 6) + (x >> 1)] = (unsigned char)seg;
        atomicAdd(&cbins[NSEG + seg], 1);
    }
    if (((y | x) & 3) == 0) {
        seg2b[(b << 10) + ((y >> 2) << 5) + (x >> 2)] = (unsigned char)seg;
        atomicAdd(&cbins[2 * NSEG + seg], 1);
    }
    if (((y | x) & 7) == 0) {
        seg3b[(b << 8) + ((y >> 3) << 4) + (x >> 3)] = (unsigned char)seg;
        atomicAdd(&cbins[3 * NSEG + seg], 1);
    }
    __syncthreads();
    if (t < 4 * NSEG) {
        int c = cbins[t];
        if (c) atomicAdd(&counts[t], c);
    }
}

// One pixel-quad's weighted SSE contribution (R7 body).
#define QACC(A, B, g) do {                                       \
    float d_;                                                    \
    d_ = (A).x - (B).x; v  = cf[(g) & 255u]         * (d_ * d_); \
    d_ = (A).y - (B).y; v += cf[((g) >> 8) & 255u]  * (d_ * d_); \
    d_ = (A).z - (B).z; v += cf[((g) >> 16) & 255u] * (d_ * d_); \
    d_ = (A).w - (B).w; v += cf[(g) >> 24]          * (d_ * d_); \
    acc += v;                                                    \
} while (0)

// Weighted SSE over nsteps 256-quad steps starting at scale-local step0.
// Addressing identical to R7's best-measured body; 4-deep load batches.
template <int S>
__device__ __forceinline__ void sq_run(const float* __restrict__ F,
                                       const float* __restrict__ O,
                                       const unsigned* __restrict__ segq,
                                       const float* __restrict__ cf,  // LDS row[17]
                                       int step0, int nsteps, float& accio)
{
    constexpr int lqpi = 12 - 2 * S;        // log2 float4-quads per (b,c) plane
    constexpr int lgBC = lqpi + 8 + S;      // log2 quads per image (C * hw4)
    constexpr int hw4m = (1 << lqpi) - 1;

    const float4* pF = reinterpret_cast<const float4*>(F);
    const float4* pO = reinterpret_cast<const float4*>(O);
    int qb = step0 * 256 + (int)threadIdx.x;

    float acc = accio;
    int i = 0;
    for (; i + 4 <= nsteps; i += 4) {
        int q0 = qb + (i + 0) * 256;
        int q1 = qb + (i + 1) * 256;
        int q2 = qb + (i + 2) * 256;
        int q3 = qb + (i + 3) * 256;
        unsigned g0 = segq[((q0 >> lgBC) << lqpi) | (q0 & hw4m)];
        unsigned g1 = segq[((q1 >> lgBC) << lqpi) | (q1 & hw4m)];
        unsigned g2 = segq[((q2 >> lgBC) << lqpi) | (q2 & hw4m)];
        unsigned g3 = segq[((q3 >> lgBC) << lqpi) | (q3 & hw4m)];
        float4 A0 = pF[q0], A1 = pF[q1], A2 = pF[q2], A3 = pF[q3];
        float4 B0 = pO[q0], B1 = pO[q1], B2 = pO[q2], B3 = pO[q3];
        float v;
        QACC(A0, B0, g0);
        QACC(A1, B1, g1);
        QACC(A2, B2, g2);
        QACC(A3, B3, g3);
    }
    for (; i < nsteps; ++i) {
        int q = qb + i * 256;
        unsigned g = segq[((q >> lgBC) << lqpi) | (q & hw4m)];
        float4 A = pF[q], B = pO[q];
        float v;
        QACC(A, B, g);
    }
    accio = acc;
}

// Uniform-duration grid: 2048 blocks x 30 steps (256 quads each).
// Global step space: s0 [0,32768) s1 [32768,49152) s2 [49152,57344) s3 [57344,61440).
// All boundaries are multiples of 256 steps >> 30, so each block crosses <=1.
__global__ __launch_bounds__(256) void sq_sum_kernel(
    const float* __restrict__ f0, const float* __restrict__ o0,
    const float* __restrict__ f1, const float* __restrict__ o1,
    const float* __restrict__ f2, const float* __restrict__ o2,
    const float* __restrict__ f3, const float* __restrict__ o3,
    const unsigned* __restrict__ seg0q, const unsigned* __restrict__ seg1q,
    const unsigned* __restrict__ seg2q, const unsigned* __restrict__ seg3q,
    const int* __restrict__ counts,   // [4][17]
    const int* __restrict__ p_ncls,
    const int* __restrict__ p_nold,
    int OC,
    float* __restrict__ out)
{
    __shared__ float cf[4][NSEG];
    __shared__ float wsum[4];

    int t = threadIdx.x;
    if (t < 4 * NSEG) {
        int s = t / NSEG, g = t % NSEG;
        int nold = p_nold[0];
        if (nold < 1 || nold > 100) nold = OC - 1;   // sanity fallback
        int ncls = p_ncls[0];
        if (ncls <= nold || ncls > 1000) ncls = 21;  // sanity fallback
        float w = (g == 0) ? (float)nold / (float)ncls
                           : ((g <= nold) ? 1.0f : 0.0f);
        int cnt = counts[t];
        float c = 0.0f;
        if (cnt > 0 && w > 0.0f)
            c = 0.25f * (float)(s + 1) * w /
                ((float)cnt * (float)(256 << s));
        cf[s][g] = c;
    }
    __syncthreads();

    int a    = blockIdx.x * 30;
    int gend = a + 30;
    float acc = 0.0f;
    while (a < gend) {
        if (a < 32768) {
            int e = (gend < 32768) ? gend : 32768;
            sq_run<0>(f0, o0, seg0q, cf[0], a, e - a, acc); a = e;
        } else if (a < 49152) {
            int e = (gend < 49152) ? gend : 49152;
            sq_run<1>(f1, o1, seg1q, cf[1], a - 32768, e - a, acc); a = e;
        } else if (a < 57344) {
            int e = (gend < 57344) ? gend : 57344;
            sq_run<2>(f2, o2, seg2q, cf[2], a - 49152, e - a, acc); a = e;
        } else {
            sq_run<3>(f3, o3, seg3q, cf[3], a - 57344, gend - a, acc); a = gend;
        }
    }

    #pragma unroll
    for (int off = 32; off > 0; off >>= 1) acc += __shfl_down(acc, off, 64);
    if ((threadIdx.x & 63) == 0) wsum[threadIdx.x >> 6] = acc;
    __syncthreads();
    if (threadIdx.x == 0)
        atomicAdd(out, (wsum[0] + wsum[1]) + (wsum[2] + wsum[3]));
}

extern "C" void kernel_launch(void* const* d_in, const int* in_sizes, int n_in,
                              void* d_out, int out_size, void* d_ws, size_t ws_size,
                              hipStream_t stream) {
    // setup_inputs dict order:
    // labels, outputs_old, feat0, feat_old0, feat1, feat_old1,
    // feat2, feat_old2, feat3, feat_old3, num_class, num_old_class
    const int*   labels      = (const int*)d_in[0];
    const float* outputs_old = (const float*)d_in[1];
    const float* f0 = (const float*)d_in[2];
    const float* o0 = (const float*)d_in[3];
    const float* f1 = (const float*)d_in[4];
    const float* o1 = (const float*)d_in[5];
    const float* f2 = (const float*)d_in[6];
    const float* o2 = (const float*)d_in[7];
    const float* f3 = (const float*)d_in[8];
    const float* o3 = (const float*)d_in[9];
    const int* p_ncls = (const int*)d_in[10];
    const int* p_nold = (const int*)d_in[11];

    int OC = in_sizes[1] / in_sizes[0];   // outputs_old channels = num_old_class + 1

    char* ws = (char*)d_ws;
    int*   counts = (int*)ws;                       // 272 B
    unsigned char* seg0b = (unsigned char*)(ws + 1024);
    unsigned char* seg1b = (unsigned char*)(ws + 132096);
    unsigned char* seg2b = (unsigned char*)(ws + 164864);
    unsigned char* seg3b = (unsigned char*)(ws + 173056);

    hipLaunchKernelGGL(init_accum, dim3(1), dim3(128), 0, stream,
                       counts, (float*)d_out);
    if (OC == 16) {
        hipLaunchKernelGGL(seg_count16_kernel, dim3(512), dim3(1024), 0, stream,
                           labels, outputs_old, seg0b, seg1b, seg2b, seg3b, counts);
    } else {
        hipLaunchKernelGGL(seg_count_kernel, dim3(512), dim3(256), 0, stream,
                           labels, outputs_old, seg0b, seg1b, seg2b, seg3b, counts, OC);
    }
    hipLaunchKernelGGL(sq_sum_kernel, dim3(2048), dim3(256), 0, stream,
                       f0, o0, f1, o1, f2, o2, f3, o3,
                       (const unsigned*)seg0b, (const unsigned*)seg1b,
                       (const unsigned*)seg2b, (const unsigned*)seg3b,
                       counts, p_ncls, p_nold, OC, (float*)d_out);
}

// Round 13
// 107.653 us; speedup vs baseline: 1.3835x; 1.0714x over previous
//
#include <hip/hip_runtime.h>

#define NSEG 17

typedef float fv4 __attribute__((ext_vector_type(4)));  // native vec for nontemporal builtin

// ---------------- ws layout ----------------
// [0,    272)            : int   counts[4][17]
// [1024,   1024+131072)  : uint8 seg0b[8*128*128]
// [132096, +32768)       : uint8 seg1b[8*64*64]
// [164864, +8192)        : uint8 seg2b[8*32*32]
// [173056, +2048)        : uint8 seg3b[8*16*16]

__global__ void init_accum(int* __restrict__ counts, float* __restrict__ out) {
    int t = threadIdx.x;
    if (t < 4 * NSEG) counts[t] = 0;
    if (t == 0) out[0] = 0.0f;
}

// ---- OC==16 fast path: 4 lanes per pixel, shuffle-merged argmax. ----
__global__ __launch_bounds__(1024) void seg_count16_kernel(
    const int* __restrict__ labels,         // [8,512,512]
    const float* __restrict__ outputs_old,  // [8,16,512,512]
    unsigned char* __restrict__ seg0b,
    unsigned char* __restrict__ seg1b,
    unsigned char* __restrict__ seg2b,
    unsigned char* __restrict__ seg3b,
    int* __restrict__ counts)               // [4][17]
{
    __shared__ int cbins[4 * NSEG];
    int t = threadIdx.x;
    if (t < 4 * NSEG) cbins[t] = 0;
    __syncthreads();

    int cg  = t & 3;                        // channel group (4 channels each)
    int pli = t >> 2;                       // pixel-local index 0..255
    int p   = blockIdx.x * 256 + pli;       // [0, 131072)
    int b = p >> 14;
    int y = (p >> 7) & 127;
    int x = p & 127;
    int y0 = y << 2, x0 = x << 2;           // sampled position in 512 grid

    const float* base = outputs_old + (((size_t)b * 16) << 18) + (y0 << 9) + x0;
    int c0 = cg << 2;
    float v0 = base[(size_t)(c0 + 0) << 18];
    float v1 = base[(size_t)(c0 + 1) << 18];
    float v2 = base[(size_t)(c0 + 2) << 18];
    float v3 = base[(size_t)(c0 + 3) << 18];
    v0 = (v0 < 0.5f) ? 0.0f : v0;
    v1 = (v1 < 0.5f) ? 0.0f : v1;
    v2 = (v2 < 0.5f) ? 0.0f : v2;
    v3 = (v3 < 0.5f) ? 0.0f : v3;

    // in-lane first-index argmax over this lane's 4 channels
    float best = v0; int bi = c0;
    if (v1 > best) { best = v1; bi = c0 + 1; }
    if (v2 > best) { best = v2; bi = c0 + 2; }
    if (v3 > best) { best = v3; bi = c0 + 3; }

    // merge across the 4 cg lanes (lane bits 0-1); min-index on ties
    #pragma unroll
    for (int m = 1; m <= 2; m <<= 1) {
        float ov = __shfl_xor(best, m, 64);
        int   oi = __shfl_xor(bi,   m, 64);
        if (ov > best || (ov == best && oi < bi)) { best = ov; bi = oi; }
    }

    if (cg == 0) {
        int lbl = labels[(b << 18) + (y0 << 9) + x0];
        int pl = (lbl == 0) ? bi : lbl;
        int seg = (pl <= 15) ? pl : 16;

        seg0b[p] = (unsigned char)seg;
        atomicAdd(&cbins[seg], 1);
        if (((y | x) & 1) == 0) {
            seg1b[(b << 12) + ((y >> 1) << 6) + (x >> 1)] = (unsigned char)seg;
            atomicAdd(&cbins[NSEG + seg], 1);
        }
        if (((y | x) & 3) == 0) {
            seg2b[(b << 10) + ((y >> 2) << 5) + (x >> 2)] = (unsigned char)seg;
            atomicAdd(&cbins[2 * NSEG + seg], 1);
        }
        if (((y | x) & 7) == 0) {
            seg3b[(b << 8) + ((y >> 3) << 4) + (x >> 3)] = (unsigned char)seg;
            atomicAdd(&cbins[3 * NSEG + seg], 1);
        }
    }
    __syncthreads();
    if (t < 4 * NSEG) {
        int c = cbins[t];
        if (c) atomicAdd(&counts[t], c);
    }
}

// ---- generic fallback (any OC), one thread per pixel ----
__global__ __launch_bounds__(256) void seg_count_kernel(
    const int* __restrict__ labels,
    const float* __restrict__ outputs_old,
    unsigned char* __restrict__ seg0b,
    unsigned char* __restrict__ seg1b,
    unsigned char* __restrict__ seg2b,
    unsigned char* __restrict__ seg3b,
    int* __restrict__ counts,
    int OC)
{
    __shared__ int cbins[4 * NSEG];
    int t = threadIdx.x;
    if (t < 4 * NSEG) cbins[t] = 0;
    __syncthreads();

    int p = blockIdx.x * 256 + t;
    int b = p >> 14;
    int y = (p >> 7) & 127;
    int x = p & 127;
    int y0 = y << 2, x0 = x << 2;

    int lbl = labels[(b << 18) + (y0 << 9) + x0];

    const float* base = outputs_old + (((size_t)b * OC) << 18) + (y0 << 9) + x0;
    float v0 = base[0];
    float best = (v0 < 0.5f) ? 0.0f : v0;
    int bidx = 0;
    #pragma unroll 4
    for (int c = 1; c < OC; ++c) {
        float v = base[(size_t)c << 18];
        v = (v < 0.5f) ? 0.0f : v;
        if (v > best) { best = v; bidx = c; }
    }

    int nold = OC - 1;
    int pl = (lbl == 0) ? bidx : lbl;
    int seg = (pl <= nold) ? pl : (nold + 1);

    seg0b[p] = (unsigned char)seg;
    atomicAdd(&cbins[seg], 1);
    if (((y | x) & 1) == 0) {
        seg1b[(b << 12) + ((y >> 1) << 6) + (x >> 1)] = (unsigned char)seg;
        atomicAdd(&cbins[NSEG + seg], 1);
    }
    if (((y | x) & 3) == 0) {
        seg2b[(b << 10) + ((y >> 2) << 5) + (x >> 2)] = (unsigned char)seg;
        atomicAdd(&cbins[2 * NSEG + seg], 1);
    }
    if (((y | x) & 7) == 0) {
        seg3b[(b << 8) + ((y >> 3) << 4) + (x >> 3)] = (unsigned char)seg;
        atomicAdd(&cbins[3 * NSEG + seg], 1);
    }
    __syncthreads();
    if (t < 4 * NSEG) {
        int c = cbins[t];
        if (c) atomicAdd(&counts[t], c);
    }
}

// One pixel-quad's weighted SSE contribution (R7 body, fv4 components).
#define QACC(A, B, g) do {                                       \
    float d_;                                                    \
    d_ = (A).x - (B).x; v  = cf[(g) & 255u]         * (d_ * d_); \
    d_ = (A).y - (B).y; v += cf[((g) >> 8) & 255u]  * (d_ * d_); \
    d_ = (A).z - (B).z; v += cf[((g) >> 16) & 255u] * (d_ * d_); \
    d_ = (A).w - (B).w; v += cf[(g) >> 24]          * (d_ * d_); \
    acc += v;                                                    \
} while (0)

// Weighted SSE over nsteps 256-quad steps starting at scale-local step0.
// R11 body with NON-TEMPORAL loads on the F/O streams (bypass LRU promotion
// in L2/L3): discriminating experiment for "L3-hit lane is the slow lane".
template <int S>
__device__ __forceinline__ void sq_run(const float* __restrict__ F,
                                       const float* __restrict__ O,
                                       const unsigned* __restrict__ segq,
                                       const float* __restrict__ cf,  // LDS row[17]
                                       int step0, int nsteps, float& accio)
{
    constexpr int lqpi = 12 - 2 * S;        // log2 float4-quads per (b,c) plane
    constexpr int lgBC = lqpi + 8 + S;      // log2 quads per image (C * hw4)
    constexpr int hw4m = (1 << lqpi) - 1;

    const fv4* pF = reinterpret_cast<const fv4*>(F);
    const fv4* pO = reinterpret_cast<const fv4*>(O);
    int qb = step0 * 256 + (int)threadIdx.x;

    float acc = accio;
    int i = 0;
    for (; i + 4 <= nsteps; i += 4) {
        int q0 = qb + (i + 0) * 256;
        int q1 = qb + (i + 1) * 256;
        int q2 = qb + (i + 2) * 256;
        int q3 = qb + (i + 3) * 256;
        unsigned g0 = segq[((q0 >> lgBC) << lqpi) | (q0 & hw4m)];
        unsigned g1 = segq[((q1 >> lgBC) << lqpi) | (q1 & hw4m)];
        unsigned g2 = segq[((q2 >> lgBC) << lqpi) | (q2 & hw4m)];
        unsigned g3 = segq[((q3 >> lgBC) << lqpi) | (q3 & hw4m)];
        fv4 A0 = __builtin_nontemporal_load(pF + q0);
        fv4 A1 = __builtin_nontemporal_load(pF + q1);
        fv4 A2 = __builtin_nontemporal_load(pF + q2);
        fv4 A3 = __builtin_nontemporal_load(pF + q3);
        fv4 B0 = __builtin_nontemporal_load(pO + q0);
        fv4 B1 = __builtin_nontemporal_load(pO + q1);
        fv4 B2 = __builtin_nontemporal_load(pO + q2);
        fv4 B3 = __builtin_nontemporal_load(pO + q3);
        float v;
        QACC(A0, B0, g0);
        QACC(A1, B1, g1);
        QACC(A2, B2, g2);
        QACC(A3, B3, g3);
    }
    for (; i < nsteps; ++i) {
        int q = qb + i * 256;
        unsigned g = segq[((q >> lgBC) << lqpi) | (q & hw4m)];
        fv4 A = __builtin_nontemporal_load(pF + q);
        fv4 B = __builtin_nontemporal_load(pO + q);
        float v;
        QACC(A, B, g);
    }
    accio = acc;
}

// Uniform-duration grid: 2048 blocks x 30 steps (256 quads each).
// Global step space: s0 [0,32768) s1 [32768,49152) s2 [49152,57344) s3 [57344,61440).
__global__ __launch_bounds__(256) void sq_sum_kernel(
    const float* __restrict__ f0, const float* __restrict__ o0,
    const float* __restrict__ f1, const float* __restrict__ o1,
    const float* __restrict__ f2, const float* __restrict__ o2,
    const float* __restrict__ f3, const float* __restrict__ o3,
    const unsigned* __restrict__ seg0q, const unsigned* __restrict__ seg1q,
    const unsigned* __restrict__ seg2q, const unsigned* __restrict__ seg3q,
    const int* __restrict__ counts,   // [4][17]
    const int* __restrict__ p_ncls,
    const int* __restrict__ p_nold,
    int OC,
    float* __restrict__ out)
{
    __shared__ float cf[4][NSEG];
    __shared__ float wsum[4];

    int t = threadIdx.x;
    if (t < 4 * NSEG) {
        int s = t / NSEG, g = t % NSEG;
        int nold = p_nold[0];
        if (nold < 1 || nold > 100) nold = OC - 1;   // sanity fallback
        int ncls = p_ncls[0];
        if (ncls <= nold || ncls > 1000) ncls = 21;  // sanity fallback
        float w = (g == 0) ? (float)nold / (float)ncls
                           : ((g <= nold) ? 1.0f : 0.0f);
        int cnt = counts[t];
        float c = 0.0f;
        if (cnt > 0 && w > 0.0f)
            c = 0.25f * (float)(s + 1) * w /
                ((float)cnt * (float)(256 << s));
        cf[s][g] = c;
    }
    __syncthreads();

    int a    = blockIdx.x * 30;
    int gend = a + 30;
    float acc = 0.0f;
    while (a < gend) {
        if (a < 32768) {
            int e = (gend < 32768) ? gend : 32768;
            sq_run<0>(f0, o0, seg0q, cf[0], a, e - a, acc); a = e;
        } else if (a < 49152) {
            int e = (gend < 49152) ? gend : 49152;
            sq_run<1>(f1, o1, seg1q, cf[1], a - 32768, e - a, acc); a = e;
        } else if (a < 57344) {
            int e = (gend < 57344) ? gend : 57344;
            sq_run<2>(f2, o2, seg2q, cf[2], a - 49152, e - a, acc); a = e;
        } else {
            sq_run<3>(f3, o3, seg3q, cf[3], a - 57344, gend - a, acc); a = gend;
        }
    }

    #pragma unroll
    for (int off = 32; off > 0; off >>= 1) acc += __shfl_down(acc, off, 64);
    if ((threadIdx.x & 63) == 0) wsum[threadIdx.x >> 6] = acc;
    __syncthreads();
    if (threadIdx.x == 0)
        atomicAdd(out, (wsum[0] + wsum[1]) + (wsum[2] + wsum[3]));
}

extern "C" void kernel_launch(void* const* d_in, const int* in_sizes, int n_in,
                              void* d_out, int out_size, void* d_ws, size_t ws_size,
                              hipStream_t stream) {
    // setup_inputs dict order:
    // labels, outputs_old, feat0, feat_old0, feat1, feat_old1,
    // feat2, feat_old2, feat3, feat_old3, num_class, num_old_class
    const int*   labels      = (const int*)d_in[0];
    const float* outputs_old = (const float*)d_in[1];
    const float* f0 = (const float*)d_in[2];
    const float* o0 = (const float*)d_in[3];
    const float* f1 = (const float*)d_in[4];
    const float* o1 = (const float*)d_in[5];
    const float* f2 = (const float*)d_in[6];
    const float* o2 = (const float*)d_in[7];
    const float* f3 = (const float*)d_in[8];
    const float* o3 = (const float*)d_in[9];
    const int* p_ncls = (const int*)d_in[10];
    const int* p_nold = (const int*)d_in[11];

    int OC = in_sizes[1] / in_sizes[0];   // outputs_old channels = num_old_class + 1

    char* ws = (char*)d_ws;
    int*   counts = (int*)ws;                       // 272 B
    unsigned char* seg0b = (unsigned char*)(ws + 1024);
    unsigned char* seg1b = (unsigned char*)(ws + 132096);
    unsigned char* seg2b = (unsigned char*)(ws + 164864);
    unsigned char* seg3b = (unsigned char*)(ws + 173056);

    hipLaunchKernelGGL(init_accum, dim3(1), dim3(128), 0, stream,
                       counts, (float*)d_out);
    if (OC == 16) {
        hipLaunchKernelGGL(seg_count16_kernel, dim3(512), dim3(1024), 0, stream,
                           labels, outputs_old, seg0b, seg1b, seg2b, seg3b, counts);
    } else {
        hipLaunchKernelGGL(seg_count_kernel, dim3(512), dim3(256), 0, stream,
                           labels, outputs_old, seg0b, seg1b, seg2b, seg3b, counts, OC);
    }
    hipLaunchKernelGGL(sq_sum_kernel, dim3(2048), dim3(256), 0, stream,
                       f0, o0, f1, o1, f2, o2, f3, o3,
                       (const unsigned*)seg0b, (const unsigned*)seg1b,
                       (const unsigned*)seg2b, (const unsigned*)seg3b,
                       counts, p_ncls, p_nold, OC, (float*)d_out);
}